// Round 2
// baseline (180.537 us; speedup 1.0000x reference)
//
#include <hip/hip_runtime.h>

// B=8, S=4096, E=256, H=4, DK=64. Tokens = B*S = 32768.
// "Attention" contracts over heads WITHIN each token (scores are (B,S,H,H)):
// 4 skinny GEMMs (32768x256 @ 256x256) + per-token 4x4 softmax mix.
// Round-2 structure: block = 32 tokens, 4 waves, whole-grid-resident.
//  - A-fragments load straight from global x (f32, L1-resident 32KB tile) with
//    in-register bf16 cvt -> no x LDS buffer, no staging phase.
//  - Per-projection sequential K-loops: only 8 f32x4 accs live (32 VGPR).
//  - 2 LDS buffers (Q->V, K->Y aliasing) = 35.8 KB -> 4 blocks/CU -> all
//    1024 blocks co-resident (256 CU x 4), zero tail.

typedef __bf16 bf16x8 __attribute__((ext_vector_type(8)));
typedef float f32x4 __attribute__((ext_vector_type(4)));

#define LDW 264   // LDS row stride in bf16 elems (256 + 8 pad; rows stay 16B-aligned)

__device__ __forceinline__ unsigned short bfs(float f) {
  __bf16 h = (__bf16)f;
  return *(unsigned short*)&h;
}

// Pack Wq|Wk|Wv|Wo (each 256x256 f32) -> Wb[1024][256] bf16. Re-run every
// launch (ws re-poisoned). 256 blocks x 256 threads, float4/ushort4.
__global__ void pack_weights(const float4* __restrict__ Wq, const float4* __restrict__ Wk,
                             const float4* __restrict__ Wv, const float4* __restrict__ Wo,
                             ushort4* __restrict__ Wb) {
  int i = blockIdx.x * 256 + threadIdx.x;   // float4-group 0..65535
  int m = i >> 14;                          // 16384 groups per 256x256 matrix
  const float4* src = (m == 0) ? Wq : (m == 1) ? Wk : (m == 2) ? Wv : Wo;
  float4 f = src[i & 16383];
  ushort4 o;
  o.x = bfs(f.x); o.y = bfs(f.y); o.z = bfs(f.z); o.w = bfs(f.w);
  Wb[i] = o;
}

// A-fragment: 8 consecutive k-elements of one x row, f32 -> bf16 in-register.
__device__ __forceinline__ bf16x8 ld_a8(const float* __restrict__ p) {
  const float4 f0 = ((const float4*)p)[0];
  const float4 f1 = ((const float4*)p)[1];
  bf16x8 r;
  r[0] = (__bf16)f0.x; r[1] = (__bf16)f0.y; r[2] = (__bf16)f0.z; r[3] = (__bf16)f0.w;
  r[4] = (__bf16)f1.x; r[5] = (__bf16)f1.y; r[6] = (__bf16)f1.z; r[7] = (__bf16)f1.w;
  return r;
}

// One 32x64 projection slice: acc[mf][nf] += x_tile @ W[pbase+n0.. , :]^T
__device__ __forceinline__ void proj(const float* __restrict__ xa0, const float* __restrict__ xa1,
                                     const __bf16* __restrict__ Wb, int pbase,
                                     int n0, int lh, int lq, f32x4 acc[2][4]) {
  const __bf16* b0 = Wb + (size_t)(pbase + n0 +  0 + lh) * 256 + lq * 8;
  const __bf16* b1 = Wb + (size_t)(pbase + n0 + 16 + lh) * 256 + lq * 8;
  const __bf16* b2 = Wb + (size_t)(pbase + n0 + 32 + lh) * 256 + lq * 8;
  const __bf16* b3 = Wb + (size_t)(pbase + n0 + 48 + lh) * 256 + lq * 8;
  #pragma unroll
  for (int kk = 0; kk < 8; ++kk) {
    bf16x8 a0 = ld_a8(xa0 + kk * 32);
    bf16x8 a1 = ld_a8(xa1 + kk * 32);
    bf16x8 w0 = *(const bf16x8*)(b0 + kk * 32);
    bf16x8 w1 = *(const bf16x8*)(b1 + kk * 32);
    bf16x8 w2 = *(const bf16x8*)(b2 + kk * 32);
    bf16x8 w3 = *(const bf16x8*)(b3 + kk * 32);
    acc[0][0] = __builtin_amdgcn_mfma_f32_16x16x32_bf16(a0, w0, acc[0][0], 0, 0, 0);
    acc[1][0] = __builtin_amdgcn_mfma_f32_16x16x32_bf16(a1, w0, acc[1][0], 0, 0, 0);
    acc[0][1] = __builtin_amdgcn_mfma_f32_16x16x32_bf16(a0, w1, acc[0][1], 0, 0, 0);
    acc[1][1] = __builtin_amdgcn_mfma_f32_16x16x32_bf16(a1, w1, acc[1][1], 0, 0, 0);
    acc[0][2] = __builtin_amdgcn_mfma_f32_16x16x32_bf16(a0, w2, acc[0][2], 0, 0, 0);
    acc[1][2] = __builtin_amdgcn_mfma_f32_16x16x32_bf16(a1, w2, acc[1][2], 0, 0, 0);
    acc[0][3] = __builtin_amdgcn_mfma_f32_16x16x32_bf16(a0, w3, acc[0][3], 0, 0, 0);
    acc[1][3] = __builtin_amdgcn_mfma_f32_16x16x32_bf16(a1, w3, acc[1][3], 0, 0, 0);
  }
}

// Scatter C/D (col=lane&15, row=(lane>>4)*4+reg) + bias -> bf16 LDS tile
__device__ __forceinline__ void store_cd(__bf16* __restrict__ buf, const f32x4 acc[2][4],
                                         const float* __restrict__ bias,
                                         int n0, int lh, int lq) {
  #pragma unroll
  for (int nf = 0; nf < 4; ++nf) {
    int col = n0 + nf * 16 + lh;
    float bb = bias[col];
    #pragma unroll
    for (int mf = 0; mf < 2; ++mf) {
      int r = mf * 16 + lq * 4;
      #pragma unroll
      for (int j = 0; j < 4; ++j)
        buf[(r + j) * LDW + col] = (__bf16)(acc[mf][nf][j] + bb);
    }
  }
}

__launch_bounds__(256, 4)
__global__ void fused_attn(const float* __restrict__ x, const __bf16* __restrict__ Wb,
                           const float* __restrict__ bq, const float* __restrict__ bk,
                           const float* __restrict__ bv, const float* __restrict__ bo,
                           float* __restrict__ out) {
  __shared__ __bf16 qs[32 * LDW];    // Q, then V (Q dead after scores)
  __shared__ __bf16 ksh[32 * LDW];   // K, then Y (K dead after scores)
  __shared__ float PL[32 * 16];      // per-token softmax probs

  const int tid  = threadIdx.x;
  const int lane = tid & 63;
  const int nw   = tid >> 6;
  const int lh   = lane & 15;
  const int lq   = lane >> 4;
  const int n0   = nw * 64;
  const int tok0 = blockIdx.x * 32;

  const float* xa0 = x + (size_t)(tok0 + lh) * 256 + lq * 8;
  const float* xa1 = xa0 + 16 * 256;

  // ---- Q projection ----
  {
    f32x4 acc[2][4];
    #pragma unroll
    for (int mf = 0; mf < 2; ++mf)
      #pragma unroll
      for (int nf = 0; nf < 4; ++nf) acc[mf][nf] = (f32x4){0.f, 0.f, 0.f, 0.f};
    proj(xa0, xa1, Wb, 0, n0, lh, lq, acc);
    store_cd(qs, acc, bq, n0, lh, lq);
  }
  // ---- K projection ----
  {
    f32x4 acc[2][4];
    #pragma unroll
    for (int mf = 0; mf < 2; ++mf)
      #pragma unroll
      for (int nf = 0; nf < 4; ++nf) acc[mf][nf] = (f32x4){0.f, 0.f, 0.f, 0.f};
    proj(xa0, xa1, Wb, 256, n0, lh, lq, acc);
    store_cd(ksh, acc, bk, n0, lh, lq);
  }
  __syncthreads();   // Q,K visible

  // ---- scores + softmax: 4 threads per token ----
  {
    const int m   = tid >> 3;
    const int sub = tid & 7;
    if (sub < 4) {
      const int h = sub;
      float d0 = 0.f, d1 = 0.f, d2 = 0.f, d3 = 0.f;
      #pragma unroll
      for (int i = 0; i < 8; ++i) {
        bf16x8 qv = *(const bf16x8*)&qs[m * LDW + h * 64 + i * 8];
        bf16x8 k0 = *(const bf16x8*)&ksh[m * LDW +   0 + i * 8];
        bf16x8 k1 = *(const bf16x8*)&ksh[m * LDW +  64 + i * 8];
        bf16x8 k2 = *(const bf16x8*)&ksh[m * LDW + 128 + i * 8];
        bf16x8 k3 = *(const bf16x8*)&ksh[m * LDW + 192 + i * 8];
        #pragma unroll
        for (int j = 0; j < 8; ++j) {
          float qf = (float)qv[j];
          d0 += qf * (float)k0[j];
          d1 += qf * (float)k1[j];
          d2 += qf * (float)k2[j];
          d3 += qf * (float)k3[j];
        }
      }
      d0 *= 0.125f; d1 *= 0.125f; d2 *= 0.125f; d3 *= 0.125f;  // 1/sqrt(64)
      float mx = fmaxf(fmaxf(d0, d1), fmaxf(d2, d3));
      float e0 = expf(d0 - mx), e1 = expf(d1 - mx), e2 = expf(d2 - mx), e3 = expf(d3 - mx);
      float inv = 1.0f / (e0 + e1 + e2 + e3);
      float* pl = &PL[m * 16 + h * 4];
      pl[0] = e0 * inv; pl[1] = e1 * inv; pl[2] = e2 * inv; pl[3] = e3 * inv;
    }
  }
  __syncthreads();   // P visible; Q,K reads complete

  // ---- V projection (overwrites Q region) ----
  {
    f32x4 acc[2][4];
    #pragma unroll
    for (int mf = 0; mf < 2; ++mf)
      #pragma unroll
      for (int nf = 0; nf < 4; ++nf) acc[mf][nf] = (f32x4){0.f, 0.f, 0.f, 0.f};
    proj(xa0, xa1, Wb, 512, n0, lh, lq, acc);
    store_cd(qs, acc, bv, n0, lh, lq);
  }
  __syncthreads();   // V visible

  // ---- y-mix: y[m, h*64+d] = sum_g P[h][g] * v[m, g*64+d]; Y -> ksh ----
  {
    const int m   = tid >> 3;
    const int sub = tid & 7;
    const int h   = sub >> 1;
    const int c0  = (sub & 1) * 32;
    const float p0 = PL[m * 16 + h * 4 + 0];
    const float p1 = PL[m * 16 + h * 4 + 1];
    const float p2 = PL[m * 16 + h * 4 + 2];
    const float p3 = PL[m * 16 + h * 4 + 3];
    #pragma unroll
    for (int dd = 0; dd < 32; dd += 8) {
      int c = c0 + dd;
      bf16x8 v0 = *(const bf16x8*)&qs[m * LDW +   0 + c];
      bf16x8 v1 = *(const bf16x8*)&qs[m * LDW +  64 + c];
      bf16x8 v2 = *(const bf16x8*)&qs[m * LDW + 128 + c];
      bf16x8 v3 = *(const bf16x8*)&qs[m * LDW + 192 + c];
      bf16x8 yv;
      #pragma unroll
      for (int j = 0; j < 8; ++j) {
        float f = p0 * (float)v0[j] + p1 * (float)v1[j]
                + p2 * (float)v2[j] + p3 * (float)v3[j];
        yv[j] = (__bf16)f;
      }
      *(bf16x8*)&ksh[m * LDW + h * 64 + c] = yv;
    }
  }
  __syncthreads();   // Y visible

  // ---- output GEMM: out = Y @ Wo^T + bo (A from LDS Y) ----
  {
    const __bf16* yp0 = &ksh[lh * LDW + lq * 8];
    const __bf16* yp1 = &ksh[(16 + lh) * LDW + lq * 8];
    const __bf16* b0 = Wb + (size_t)(768 + n0 +  0 + lh) * 256 + lq * 8;
    const __bf16* b1 = Wb + (size_t)(768 + n0 + 16 + lh) * 256 + lq * 8;
    const __bf16* b2 = Wb + (size_t)(768 + n0 + 32 + lh) * 256 + lq * 8;
    const __bf16* b3 = Wb + (size_t)(768 + n0 + 48 + lh) * 256 + lq * 8;

    f32x4 acc[2][4];
    #pragma unroll
    for (int mf = 0; mf < 2; ++mf)
      #pragma unroll
      for (int nf = 0; nf < 4; ++nf) acc[mf][nf] = (f32x4){0.f, 0.f, 0.f, 0.f};

    #pragma unroll
    for (int kk = 0; kk < 8; ++kk) {
      bf16x8 a0 = *(const bf16x8*)(yp0 + kk * 32);
      bf16x8 a1 = *(const bf16x8*)(yp1 + kk * 32);
      bf16x8 w0 = *(const bf16x8*)(b0 + kk * 32);
      bf16x8 w1 = *(const bf16x8*)(b1 + kk * 32);
      bf16x8 w2 = *(const bf16x8*)(b2 + kk * 32);
      bf16x8 w3 = *(const bf16x8*)(b3 + kk * 32);
      acc[0][0] = __builtin_amdgcn_mfma_f32_16x16x32_bf16(a0, w0, acc[0][0], 0, 0, 0);
      acc[1][0] = __builtin_amdgcn_mfma_f32_16x16x32_bf16(a1, w0, acc[1][0], 0, 0, 0);
      acc[0][1] = __builtin_amdgcn_mfma_f32_16x16x32_bf16(a0, w1, acc[0][1], 0, 0, 0);
      acc[1][1] = __builtin_amdgcn_mfma_f32_16x16x32_bf16(a1, w1, acc[1][1], 0, 0, 0);
      acc[0][2] = __builtin_amdgcn_mfma_f32_16x16x32_bf16(a0, w2, acc[0][2], 0, 0, 0);
      acc[1][2] = __builtin_amdgcn_mfma_f32_16x16x32_bf16(a1, w2, acc[1][2], 0, 0, 0);
      acc[0][3] = __builtin_amdgcn_mfma_f32_16x16x32_bf16(a0, w3, acc[0][3], 0, 0, 0);
      acc[1][3] = __builtin_amdgcn_mfma_f32_16x16x32_bf16(a1, w3, acc[1][3], 0, 0, 0);
    }

    #pragma unroll
    for (int nf = 0; nf < 4; ++nf) {
      int col = n0 + nf * 16 + lh;
      float bb = bo[col];
      #pragma unroll
      for (int mf = 0; mf < 2; ++mf) {
        int rbase = tok0 + mf * 16 + lq * 4;
        #pragma unroll
        for (int j = 0; j < 4; ++j)
          out[(size_t)(rbase + j) * 256 + col] = acc[mf][nf][j] + bb;
      }
    }
  }
}

extern "C" void kernel_launch(void* const* d_in, const int* in_sizes, int n_in,
                              void* d_out, int out_size, void* d_ws, size_t ws_size,
                              hipStream_t stream) {
  const float* x  = (const float*)d_in[0];
  const float* Wq = (const float*)d_in[1];
  const float* bq = (const float*)d_in[2];
  const float* Wk = (const float*)d_in[3];
  const float* bk = (const float*)d_in[4];
  const float* Wv = (const float*)d_in[5];
  const float* bv = (const float*)d_in[6];
  const float* Wo = (const float*)d_in[7];
  const float* bo = (const float*)d_in[8];
  float* out = (float*)d_out;
  __bf16* Wb = (__bf16*)d_ws;   // 1024x256 bf16 = 512 KB

  pack_weights<<<dim3(256), dim3(256), 0, stream>>>(
      (const float4*)Wq, (const float4*)Wk, (const float4*)Wv, (const float4*)Wo,
      (ushort4*)Wb);
  fused_attn<<<dim3(1024), dim3(256), 0, stream>>>(x, Wb, bq, bk, bv, bo, out);
}

// Round 3
// 128.773 us; speedup vs baseline: 1.4020x; 1.4020x over previous
//
#include <hip/hip_runtime.h>

// B=8, S=4096, E=256, H=4, DK=64. Tokens = B*S = 32768.
// "Attention" contracts over heads WITHIN each token: 4 skinny GEMMs
// (32768x256 @ 256x256) + per-token 4x4 softmax mix.
// Round-3: kill scattered global fragment loads (round-1/2 latency killer).
//  - Weights pre-packed so every B-fragment is a contiguous 1KB (lane*16B).
//  - x staged to LDS with lane-contiguous float4 loads; A-frags via ds_read_b128
//    from +8-padded LDS (2-way bank aliasing = free on gfx950).
//  - M=32/block, LDS 52.7KB, 3 blocks/CU (__launch_bounds__(256,3)).

typedef __bf16 bf16x8 __attribute__((ext_vector_type(8)));
typedef __bf16 bf16x4 __attribute__((ext_vector_type(4)));
typedef float f32x4 __attribute__((ext_vector_type(4)));

#define LDW 264   // LDS row stride in bf16 elems (256+8 pad; rows stay 16B-aligned)

// ---------- prep: pack W into fragment-contiguous bf16 ----------
// Fragment (p, nw, nf, kk): lane(lh=lane&15, lq=lane>>4) holds
//   W_p[nw*64 + nf*16 + lh][kk*32 + lq*8 + j], j=0..7  (8 bf16 = 16B)
// stored at Wpk[frag_id*512 + lane*8], frag_id = ((p*4+nw)*4+nf)*8+kk.
// 512 frags x 1KB = 512 KB. Re-run every launch (ws re-poisoned).
__global__ void pack_wfrag(const float* __restrict__ Wq, const float* __restrict__ Wk,
                           const float* __restrict__ Wv, const float* __restrict__ Wo,
                           __bf16* __restrict__ Wpk) {
  const int f    = blockIdx.x;          // 0..511
  const int lane = threadIdx.x;         // 0..63
  const int kk = f & 7;
  const int nf = (f >> 3) & 3;
  const int nw = (f >> 5) & 3;
  const int p  = f >> 7;
  const float* W = (p == 0) ? Wq : (p == 1) ? Wk : (p == 2) ? Wv : Wo;
  const int lh = lane & 15, lq = lane >> 4;
  const int n  = nw * 64 + nf * 16 + lh;
  const int k0 = kk * 32 + lq * 8;
  const float4 s0 = *(const float4*)&W[n * 256 + k0];
  const float4 s1 = *(const float4*)&W[n * 256 + k0 + 4];
  bf16x8 r;
  r[0] = (__bf16)s0.x; r[1] = (__bf16)s0.y; r[2] = (__bf16)s0.z; r[3] = (__bf16)s0.w;
  r[4] = (__bf16)s1.x; r[5] = (__bf16)s1.y; r[6] = (__bf16)s1.z; r[7] = (__bf16)s1.w;
  *(bf16x8*)&Wpk[(size_t)f * 512 + lane * 8] = r;
}

// ---------- fused attention ----------
// One 32x64 projection slice; A-frags from LDS xs, B-frags from packed global.
__device__ __forceinline__ void proj(const __bf16* __restrict__ xs,
                                     const __bf16* __restrict__ wbase,  // + (nf*8+kk)*512 + lane*8
                                     int lh, int lq, int lane, f32x4 acc[2][4]) {
  const __bf16* a0p = xs + lh * LDW + lq * 8;
  const __bf16* a1p = a0p + 16 * LDW;
  const __bf16* wl  = wbase + lane * 8;
  #pragma unroll
  for (int kk = 0; kk < 8; ++kk) {
    bf16x8 a0 = *(const bf16x8*)(a0p + kk * 32);
    bf16x8 a1 = *(const bf16x8*)(a1p + kk * 32);
    bf16x8 w0 = *(const bf16x8*)(wl + (0 * 8 + kk) * 512);
    bf16x8 w1 = *(const bf16x8*)(wl + (1 * 8 + kk) * 512);
    bf16x8 w2 = *(const bf16x8*)(wl + (2 * 8 + kk) * 512);
    bf16x8 w3 = *(const bf16x8*)(wl + (3 * 8 + kk) * 512);
    acc[0][0] = __builtin_amdgcn_mfma_f32_16x16x32_bf16(a0, w0, acc[0][0], 0, 0, 0);
    acc[1][0] = __builtin_amdgcn_mfma_f32_16x16x32_bf16(a1, w0, acc[1][0], 0, 0, 0);
    acc[0][1] = __builtin_amdgcn_mfma_f32_16x16x32_bf16(a0, w1, acc[0][1], 0, 0, 0);
    acc[1][1] = __builtin_amdgcn_mfma_f32_16x16x32_bf16(a1, w1, acc[1][1], 0, 0, 0);
    acc[0][2] = __builtin_amdgcn_mfma_f32_16x16x32_bf16(a0, w2, acc[0][2], 0, 0, 0);
    acc[1][2] = __builtin_amdgcn_mfma_f32_16x16x32_bf16(a1, w2, acc[1][2], 0, 0, 0);
    acc[0][3] = __builtin_amdgcn_mfma_f32_16x16x32_bf16(a0, w3, acc[0][3], 0, 0, 0);
    acc[1][3] = __builtin_amdgcn_mfma_f32_16x16x32_bf16(a1, w3, acc[1][3], 0, 0, 0);
  }
}

__device__ __forceinline__ void store_cd(__bf16* __restrict__ buf, const f32x4 acc[2][4],
                                         const float* __restrict__ bias,
                                         int n0, int lh, int lq) {
  #pragma unroll
  for (int nf = 0; nf < 4; ++nf) {
    int col = n0 + nf * 16 + lh;
    float bb = bias[col];
    #pragma unroll
    for (int mf = 0; mf < 2; ++mf) {
      int r = mf * 16 + lq * 4;
      #pragma unroll
      for (int j = 0; j < 4; ++j)
        buf[(r + j) * LDW + col] = (__bf16)(acc[mf][nf][j] + bb);
    }
  }
}

__launch_bounds__(256, 3)
__global__ void fused_attn(const float* __restrict__ x, const __bf16* __restrict__ Wpk,
                           const float* __restrict__ bq, const float* __restrict__ bk,
                           const float* __restrict__ bv, const float* __restrict__ bo,
                           float* __restrict__ out) {
  __shared__ __bf16 xs[32 * LDW];    // x tile (live through V projection)
  __shared__ __bf16 qs[32 * LDW];    // Q, then V
  __shared__ __bf16 ksh[32 * LDW];   // K, then Y
  __shared__ float PL[32 * 16];

  const int tid  = threadIdx.x;
  const int lane = tid & 63;
  const int nw   = tid >> 6;
  const int lh   = lane & 15;
  const int lq   = lane >> 4;
  const int n0   = nw * 64;
  const int tok0 = blockIdx.x * 32;

  // ---- stage x tile: lane-contiguous float4 loads -> bf16 padded LDS ----
  const float4* xg = (const float4*)(x + (size_t)tok0 * 256);
  #pragma unroll
  for (int i = 0; i < 8; ++i) {
    int idx = i * 256 + tid;           // float4 id, 0..2047
    int row = idx >> 6;                // 64 float4 per row
    int c4  = idx & 63;
    float4 v = xg[idx];
    bf16x4 pk;
    pk[0] = (__bf16)v.x; pk[1] = (__bf16)v.y; pk[2] = (__bf16)v.z; pk[3] = (__bf16)v.w;
    *(bf16x4*)&xs[row * LDW + c4 * 4] = pk;
  }
  __syncthreads();

  // per-(proj,wave) packed-weight base: frag_id = ((p*4+nw)*4+nf)*8+kk
  const __bf16* wqb = Wpk + (size_t)((0 * 4 + nw) * 4) * 8 * 512;
  const __bf16* wkb = Wpk + (size_t)((1 * 4 + nw) * 4) * 8 * 512;
  const __bf16* wvb = Wpk + (size_t)((2 * 4 + nw) * 4) * 8 * 512;
  const __bf16* wob = Wpk + (size_t)((3 * 4 + nw) * 4) * 8 * 512;

  // ---- Q projection ----
  {
    f32x4 acc[2][4];
    #pragma unroll
    for (int mf = 0; mf < 2; ++mf)
      #pragma unroll
      for (int nf = 0; nf < 4; ++nf) acc[mf][nf] = (f32x4){0.f, 0.f, 0.f, 0.f};
    proj(xs, wqb, lh, lq, lane, acc);
    store_cd(qs, acc, bq, n0, lh, lq);
  }
  // ---- K projection ----
  {
    f32x4 acc[2][4];
    #pragma unroll
    for (int mf = 0; mf < 2; ++mf)
      #pragma unroll
      for (int nf = 0; nf < 4; ++nf) acc[mf][nf] = (f32x4){0.f, 0.f, 0.f, 0.f};
    proj(xs, wkb, lh, lq, lane, acc);
    store_cd(ksh, acc, bk, n0, lh, lq);
  }
  __syncthreads();   // Q,K visible

  // ---- scores + softmax: 4 active threads per token ----
  {
    const int m   = tid >> 3;
    const int sub = tid & 7;
    if (sub < 4) {
      const int h = sub;
      float d0 = 0.f, d1 = 0.f, d2 = 0.f, d3 = 0.f;
      #pragma unroll
      for (int i = 0; i < 8; ++i) {
        bf16x8 qv = *(const bf16x8*)&qs[m * LDW + h * 64 + i * 8];
        bf16x8 k0 = *(const bf16x8*)&ksh[m * LDW +   0 + i * 8];
        bf16x8 k1 = *(const bf16x8*)&ksh[m * LDW +  64 + i * 8];
        bf16x8 k2 = *(const bf16x8*)&ksh[m * LDW + 128 + i * 8];
        bf16x8 k3 = *(const bf16x8*)&ksh[m * LDW + 192 + i * 8];
        #pragma unroll
        for (int j = 0; j < 8; ++j) {
          float qf = (float)qv[j];
          d0 += qf * (float)k0[j];
          d1 += qf * (float)k1[j];
          d2 += qf * (float)k2[j];
          d3 += qf * (float)k3[j];
        }
      }
      d0 *= 0.125f; d1 *= 0.125f; d2 *= 0.125f; d3 *= 0.125f;  // 1/sqrt(64)
      float mx = fmaxf(fmaxf(d0, d1), fmaxf(d2, d3));
      float e0 = expf(d0 - mx), e1 = expf(d1 - mx), e2 = expf(d2 - mx), e3 = expf(d3 - mx);
      float inv = 1.0f / (e0 + e1 + e2 + e3);
      float* pl = &PL[m * 16 + h * 4];
      pl[0] = e0 * inv; pl[1] = e1 * inv; pl[2] = e2 * inv; pl[3] = e3 * inv;
    }
  }
  __syncthreads();   // P visible; Q,K reads complete

  // ---- V projection (overwrites Q region) ----
  {
    f32x4 acc[2][4];
    #pragma unroll
    for (int mf = 0; mf < 2; ++mf)
      #pragma unroll
      for (int nf = 0; nf < 4; ++nf) acc[mf][nf] = (f32x4){0.f, 0.f, 0.f, 0.f};
    proj(xs, wvb, lh, lq, lane, acc);
    store_cd(qs, acc, bv, n0, lh, lq);
  }
  __syncthreads();   // V visible

  // ---- y-mix: y[m, h*64+d] = sum_g P[h][g] * v[m, g*64+d]; Y -> ksh ----
  {
    const int m   = tid >> 3;
    const int sub = tid & 7;
    const int h   = sub >> 1;
    const int c0  = (sub & 1) * 32;
    const float p0 = PL[m * 16 + h * 4 + 0];
    const float p1 = PL[m * 16 + h * 4 + 1];
    const float p2 = PL[m * 16 + h * 4 + 2];
    const float p3 = PL[m * 16 + h * 4 + 3];
    #pragma unroll
    for (int dd = 0; dd < 32; dd += 8) {
      int c = c0 + dd;
      bf16x8 v0 = *(const bf16x8*)&qs[m * LDW +   0 + c];
      bf16x8 v1 = *(const bf16x8*)&qs[m * LDW +  64 + c];
      bf16x8 v2 = *(const bf16x8*)&qs[m * LDW + 128 + c];
      bf16x8 v3 = *(const bf16x8*)&qs[m * LDW + 192 + c];
      bf16x8 yv;
      #pragma unroll
      for (int j = 0; j < 8; ++j) {
        float f = p0 * (float)v0[j] + p1 * (float)v1[j]
                + p2 * (float)v2[j] + p3 * (float)v3[j];
        yv[j] = (__bf16)f;
      }
      *(bf16x8*)&ksh[m * LDW + h * 64 + c] = yv;
    }
  }
  __syncthreads();   // Y visible

  // ---- output GEMM: out = Y @ Wo^T + bo (A from LDS Y in ksh) ----
  {
    f32x4 acc[2][4];
    #pragma unroll
    for (int mf = 0; mf < 2; ++mf)
      #pragma unroll
      for (int nf = 0; nf < 4; ++nf) acc[mf][nf] = (f32x4){0.f, 0.f, 0.f, 0.f};
    proj(ksh, wob, lh, lq, lane, acc);

    #pragma unroll
    for (int nf = 0; nf < 4; ++nf) {
      int col = n0 + nf * 16 + lh;
      float bb = bo[col];
      #pragma unroll
      for (int mf = 0; mf < 2; ++mf) {
        int rbase = tok0 + mf * 16 + lq * 4;
        #pragma unroll
        for (int j = 0; j < 4; ++j)
          out[(size_t)(rbase + j) * 256 + col] = acc[mf][nf][j] + bb;
      }
    }
  }
}

extern "C" void kernel_launch(void* const* d_in, const int* in_sizes, int n_in,
                              void* d_out, int out_size, void* d_ws, size_t ws_size,
                              hipStream_t stream) {
  const float* x  = (const float*)d_in[0];
  const float* Wq = (const float*)d_in[1];
  const float* bq = (const float*)d_in[2];
  const float* Wk = (const float*)d_in[3];
  const float* bk = (const float*)d_in[4];
  const float* Wv = (const float*)d_in[5];
  const float* bv = (const float*)d_in[6];
  const float* Wo = (const float*)d_in[7];
  const float* bo = (const float*)d_in[8];
  float* out = (float*)d_out;
  __bf16* Wpk = (__bf16*)d_ws;   // 512 frags x 1KB = 512 KB

  pack_wfrag<<<dim3(512), dim3(64), 0, stream>>>(Wq, Wk, Wv, Wo, Wpk);
  fused_attn<<<dim3(1024), dim3(256), 0, stream>>>(x, Wpk, bq, bk, bv, bo, out);
}